// Round 6
// baseline (310.639 us; speedup 1.0000x reference)
//
#include <hip/hip_runtime.h>

// MHA forward, MI355X gfx950. B=4 D=1024 S=2048 H=16 hd=64.
// R12: attn TLP fix. R8-R11 all show MFMA-busy ~33us + VALU-busy ~40us with
// idle varying by structure — pipes only overlap via OTHER waves, and
// 32 q/wave capped the kernel at 4096 waves (16/CU). Now 16 q/wave ->
// 8192 waves (32/CU): KVBLK 32, LDS 16KB (2x4K K + 2x4K V), grid (64,32)
// = 2048 blocks = 8 blocks/CU, launch_bounds(256,8) (~60 VGPR fits 64 cap).
// Per-tile math = R8's verified block minus the i-dimension. V swizzle
// re-derived for 64B rows: phys chunk = logical ^ ((d>>1)&3) -> 2-way
// (free); K swizzle unchanged (128B rows). GEMMs unchanged.

typedef __bf16 bf16;
typedef __attribute__((ext_vector_type(8))) __bf16 bf16x8;
typedef __attribute__((ext_vector_type(4))) __bf16 bf16x4;
typedef __attribute__((ext_vector_type(2))) __bf16 bf16x2;
typedef __attribute__((ext_vector_type(4))) float f32x4;
typedef __attribute__((ext_vector_type(2))) unsigned int uintx2;
typedef __attribute__((ext_vector_type(4))) unsigned int uintx4;

#define NB 4
#define ND 1024
#define NS 2048
#define NH 16
#define NM 8192  // NB*NS

__device__ __forceinline__ void gld16(const void* g, void* l) {
  __builtin_amdgcn_global_load_lds((__attribute__((address_space(1))) void*)g,
                                   (__attribute__((address_space(3))) void*)l, 16, 0, 0);
}

__device__ __forceinline__ float exp2_fast(float x) {
#if __has_builtin(__builtin_amdgcn_exp2f)
  return __builtin_amdgcn_exp2f(x);
#else
  return exp2f(x);
#endif
}

__device__ __forceinline__ unsigned pk2(float a, float b) {
  bf16x2 t;
  t[0] = (bf16)a;
  t[1] = (bf16)b;
  return __builtin_bit_cast(unsigned int, t);
}

// Exchange within lane groups {rl, rl+16, rl+32, rl+48}: perfect shuffle of
// the swapped-QK^T C-layout dwords into the PV A-operand dword layout.
__device__ __forceinline__ void lane_xchg(unsigned a, unsigned b, unsigned& lo,
                                          unsigned& hi) {
#if __has_builtin(__builtin_amdgcn_permlane32_swap) && \
    __has_builtin(__builtin_amdgcn_permlane16_swap)
  uintx2 r = __builtin_amdgcn_permlane32_swap(a, b, false, false);
  uintx2 r2 = __builtin_amdgcn_permlane16_swap(r[0], r[1], false, false);
  lo = r2[0];
  hi = r2[1];
#else
  const int lane = threadIdx.x & 63;
  const int src = (lane & 15) + ((lane >> 4) & 1) * 32;
  const unsigned as = (unsigned)__shfl((int)a, src, 64);
  const unsigned bs = (unsigned)__shfl((int)b, src, 64);
  const unsigned as2 = (unsigned)__shfl((int)a, src + 16, 64);
  const unsigned bs2 = (unsigned)__shfl((int)b, src + 16, 64);
  lo = (lane >= 32) ? bs : as;
  hi = (lane >= 32) ? bs2 : as2;
#endif
}

// ===================== prep_x: xT[b*S+s][d] = bf16(x[b][d][s] + PE[d][s]) ===
__global__ __launch_bounds__(256) void prep_x_kernel(const float* __restrict__ x,
                                                     bf16* __restrict__ xT) {
  __shared__ float t[32][33];
  const int tx = threadIdx.x, ty = threadIdx.y;
  const int s0 = blockIdx.x * 32, d0 = blockIdx.y * 32, b = blockIdx.z;
#pragma unroll
  for (int i = 0; i < 4; ++i) {
    const int rr = ty + i * 8;
    const int d = d0 + rr, s = s0 + tx;
    const float freq = __expf(-(float)(d >> 1) * 0.01798894603980689f);
    const float ang = (float)s * freq;
    const float pe = (d & 1) ? cosf(ang) : sinf(ang);  // precise: ang up to 2047 rad
    t[rr][tx] = x[((size_t)b * ND + d) * NS + s] + pe;
  }
  __syncthreads();
#pragma unroll
  for (int i = 0; i < 4; ++i) {
    const int a = ty + i * 8;  // s offset
    xT[((size_t)b * NS + s0 + a) * ND + d0 + tx] = (bf16)t[tx][a];
  }
}

// ===================== prep_w: Wq|Wk|Wv -> Wqkv bf16 [3072][1024]; Wo -> bf16
__global__ __launch_bounds__(256) void prep_w_kernel(const float* __restrict__ Wq,
                                                     const float* __restrict__ Wk,
                                                     const float* __restrict__ Wv,
                                                     const float* __restrict__ Wo,
                                                     bf16* __restrict__ Wqkv,
                                                     bf16* __restrict__ WoB) {
  const size_t t = (size_t)blockIdx.x * blockDim.x + threadIdx.x;
  const size_t i = t * 4;
  const float* src;
  bf16* dst;
  size_t off;
  if (i < (size_t)3 * 1024 * 1024) {
    const int sel = (int)(i >> 20);
    src = sel == 0 ? Wq : (sel == 1 ? Wk : Wv);
    off = i - ((size_t)sel << 20);
    dst = Wqkv + i;
  } else {
    src = Wo;
    off = i - ((size_t)3 << 20);
    dst = WoB + off;
  }
  const f32x4 v = *(const f32x4*)(src + off);
  bf16x4 o;
  o[0] = (bf16)v[0];
  o[1] = (bf16)v[1];
  o[2] = (bf16)v[2];
  o[3] = (bf16)v[3];
  *(bf16x4*)dst = o;
}

// ============ shared 128x128 GEMM mainloop, BK=64 (A [M,K], B [N,K], K=1024)
__device__ __forceinline__ void gemm_tile_128(const bf16* __restrict__ A,
                                              const bf16* __restrict__ Bm,
                                              int tm, int tn, bf16* ldsA, bf16* ldsB,
                                              f32x4 acc[4][4]) {
  const int tid = threadIdx.x;
  const int lane = tid & 63, wave = tid >> 6;
  const int wm = wave >> 1, wn = wave & 1;
  const int rl = lane & 15, quad = lane >> 4;
  int r0[4], c0[4];
#pragma unroll
  for (int j = 0; j < 4; ++j) {
    const int o = (wave * 4 + j) * 1024 + lane * 16;  // byte offset in 16KB tile
    const int r = o >> 7;                             // row (128B rows)
    r0[j] = r;
    c0[j] = ((((o >> 4) & 7) ^ (r & 7)) * 8);  // element col, XOR swizzled
  }
  for (int kt = 0; kt < 1024; kt += 64) {
#pragma unroll
    for (int j = 0; j < 4; ++j) {
      gld16(A + (size_t)(tm + r0[j]) * 1024 + kt + c0[j], (char*)ldsA + (wave * 4 + j) * 1024);
      gld16(Bm + (size_t)(tn + r0[j]) * 1024 + kt + c0[j], (char*)ldsB + (wave * 4 + j) * 1024);
    }
    __syncthreads();
#pragma unroll
    for (int kk = 0; kk < 2; ++kk) {
      bf16x8 af[4], bfr[4];
#pragma unroll
      for (int i = 0; i < 4; ++i) {
        const int ra = wm * 64 + i * 16 + rl;
        af[i] = *(const bf16x8*)((const char*)ldsA + ra * 128 +
                                 (((kk * 4 + quad) ^ (rl & 7)) * 16));
        const int rb = wn * 64 + i * 16 + rl;
        bfr[i] = *(const bf16x8*)((const char*)ldsB + rb * 128 +
                                  (((kk * 4 + quad) ^ (rl & 7)) * 16));
      }
#pragma unroll
      for (int i = 0; i < 4; ++i)
#pragma unroll
        for (int j = 0; j < 4; ++j)
          acc[i][j] =
              __builtin_amdgcn_mfma_f32_16x16x32_bf16(af[i], bfr[j], acc[i][j], 0, 0, 0);
    }
    __syncthreads();
  }
}

// ===================== QKV projection GEMM ==================================
__global__ __launch_bounds__(256, 2) void gemm_qkv_kernel(
    const bf16* __restrict__ xT, const bf16* __restrict__ Wqkv,
    const float* __restrict__ bq, const float* __restrict__ bk,
    const float* __restrict__ bv, bf16* __restrict__ Q, bf16* __restrict__ Kb,
    bf16* __restrict__ VT) {
  __shared__ bf16 ldsA[128 * 64], ldsB[128 * 64];
  const int tm = blockIdx.x * 128, tn = blockIdx.y * 128;
  f32x4 acc[4][4];
  const f32x4 z = {0.f, 0.f, 0.f, 0.f};
#pragma unroll
  for (int i = 0; i < 4; ++i)
#pragma unroll
    for (int j = 0; j < 4; ++j) acc[i][j] = z;
  gemm_tile_128(xT, Wqkv, tm, tn, ldsA, ldsB, acc);
  const int lane = threadIdx.x & 63, wave = threadIdx.x >> 6;
  const int wm = wave >> 1, wn = wave & 1;
  const int rl = lane & 15, quad = lane >> 4;
  // Q scale folds 1/sqrt(64) * log2(e) so attn uses raw 2^x
  const float QSCALE = 0.18033688011112042f;
#pragma unroll
  for (int j = 0; j < 4; ++j) {
    const int n = tn + wn * 64 + j * 16 + rl;  // 0..3071
    const int which = n >> 10;                 // uniform per block
    const int nl = n & 1023;
    const int h = nl >> 6, d = nl & 63;
    const float bias = (which == 0 ? bq : which == 1 ? bk : bv)[nl];
#pragma unroll
    for (int i = 0; i < 4; ++i) {
      const int m0 = tm + wm * 64 + i * 16 + quad * 4;
      const int b = m0 >> 11, s0 = m0 & 2047;
      const size_t bh = (size_t)(b * 16 + h);
      if (which == 2) {
        bf16x4 pk;
#pragma unroll
        for (int r = 0; r < 4; ++r) pk[r] = (bf16)(acc[i][j][r] + bias);
        *(bf16x4*)(VT + ((size_t)bh * 64 + d) * 2048 + s0) = pk;  // V^T packed
      } else {
#pragma unroll
        for (int r = 0; r < 4; ++r) {
          const float v = acc[i][j][r] + bias;
          const int s = s0 + r;
          if (which == 0)
            Q[(bh * 2048 + s) * 64 + d] = (bf16)(v * QSCALE);
          else
            Kb[(bh * 2048 + s) * 64 + d] = (bf16)v;
        }
      }
    }
  }
}

// ===================== flash attention ======================================
// grid (B*H=64, S/64=32): bh%8 = XCD pinning. 64 q/block, 16 q/wave,
// KVBLK=32, LDS 16KB -> 8 blocks/CU resident (32 waves/CU): TLP covers the
// QK->exp->PV serial chain across waves. Per-tile math = R8's verified
// 32-key block. K LDS rows 128B, chunk^(row&7) swizzle (2-way, free).
// V LDS rows 64B: phys chunk = logical ^ ((d>>1)&3) -> 2-way, free.
__global__ __launch_bounds__(256, 8) void attn_kernel(const bf16* __restrict__ Q,
                                                      const bf16* __restrict__ Kb,
                                                      const bf16* __restrict__ VT,
                                                      bf16* __restrict__ AO) {
  __shared__ __align__(16) char smem[16384];
  char* ldsK = smem;          // 2 x 4 KB (double buffer)
  char* ldsV = smem + 8192;   // 2 x 4 KB (double buffer)
  const int tid = threadIdx.x;
  const int lane = tid & 63, wave = tid >> 6;
  const int rl = lane & 15, quad = lane >> 4;
  const int bh = blockIdx.x;
  const int q0 = blockIdx.y * 64 + wave * 16;
  const bf16* Qb = Q + ((size_t)bh * 2048 + q0) * 64;
  const bf16* Kbb = Kb + (size_t)bh * 2048 * 64;
  const bf16* Vb = VT + (size_t)bh * 64 * 2048;
  // --- staging geometry (per thread: one 16B chunk into each 4KB tile) ---
  // K tile: 32 key-rows x 128B; phys chunk = logical ^ (row&7)
  const int krow = tid >> 3;
  const int kcl = (tid & 7) ^ (krow & 7);
  const size_t ksrc = (size_t)krow * 128 + (size_t)kcl * 16;  // + kt*128
  // V tile: 64 d-rows x 64B; phys chunk = logical ^ ((d>>1)&3)
  const int vd = tid >> 2;
  const int vcl = (tid & 3) ^ ((tid >> 3) & 3);
  const size_t vsrc = (size_t)vd * 4096 + (size_t)vcl * 16;  // + kt*2
  auto stage = [&](int kt, int nb) {
    gld16((const char*)Kbb + (size_t)kt * 128 + ksrc, ldsK + nb + tid * 16);
    gld16((const char*)Vb + (size_t)kt * 2 + vsrc, ldsV + nb + tid * 16);
  };
  stage(0, 0);
  // Q fragments (read exactly once; aligned 16B)
  bf16x8 qf[2];
#pragma unroll
  for (int dh = 0; dh < 2; ++dh)
    qf[dh] = *(const bf16x8*)(Qb + rl * 64 + dh * 32 + quad * 8);
  f32x4 o_acc[4], lacc;
  const f32x4 z = {0.f, 0.f, 0.f, 0.f};
  lacc = z;
#pragma unroll
  for (int j = 0; j < 4; ++j) o_acc[j] = z;
  const bf16 oneb = (bf16)1.0f;
  const bf16x8 onesb = {oneb, oneb, oneb, oneb, oneb, oneb, oneb, oneb};
  // --- read offsets (precomputed, bytes) ---
  const int kx0 = (quad ^ (rl & 7)) * 16 + rl * 128;        // d 0..31
  const int kx1 = ((4 + quad) ^ (rl & 7)) * 16 + rl * 128;  // d 32..63
  const int vx = (quad ^ ((rl >> 1) & 3)) * 16 + rl * 64;
  int buf = 0;
  for (int kt = 0; kt < 2048; kt += 32, buf ^= 1) {
    __syncthreads();  // buf landed (vmcnt drain); buf^1 free for prefetch
    if (kt + 32 < 2048) stage(kt + 32, (buf ^ 1) * 4096);
    const char* Kb0 = ldsK + buf * 4096;
    const char* Vb0 = ldsV + buf * 4096;
    const bf16x8 k00 = *(const bf16x8*)(Kb0 + kx0);
    const bf16x8 k01 = *(const bf16x8*)(Kb0 + kx1);
    const bf16x8 k10 = *(const bf16x8*)(Kb0 + 2048 + kx0);
    const bf16x8 k11 = *(const bf16x8*)(Kb0 + 2048 + kx1);
    __builtin_amdgcn_s_setprio(1);
    f32x4 s0 = __builtin_amdgcn_mfma_f32_16x16x32_bf16(k00, qf[0], z, 0, 0, 0);
    s0 = __builtin_amdgcn_mfma_f32_16x16x32_bf16(k01, qf[1], s0, 0, 0, 0);
    f32x4 s1 = __builtin_amdgcn_mfma_f32_16x16x32_bf16(k10, qf[0], z, 0, 0, 0);
    s1 = __builtin_amdgcn_mfma_f32_16x16x32_bf16(k11, qf[1], s1, 0, 0, 0);
    __builtin_amdgcn_s_setprio(0);
    // lane holds P[q=rl][key jk*16+quad*4+r] -> pack + in-register transpose
    const unsigned a0 = pk2(exp2_fast(s0[0]), exp2_fast(s0[1]));
    const unsigned a1 = pk2(exp2_fast(s0[2]), exp2_fast(s0[3]));
    const unsigned b0 = pk2(exp2_fast(s1[0]), exp2_fast(s1[1]));
    const unsigned b1 = pk2(exp2_fast(s1[2]), exp2_fast(s1[3]));
    unsigned d0, d1, d2, d3;
    lane_xchg(a0, b0, d0, d2);  // keys 8q+{0,1} and 8q+{4,5}
    lane_xchg(a1, b1, d1, d3);  // keys 8q+{2,3} and 8q+{6,7}
    uintx4 dd;
    dd[0] = d0;
    dd[1] = d1;
    dd[2] = d2;
    dd[3] = d3;
    const bf16x8 pf = __builtin_bit_cast(bf16x8, dd);
    bf16x8 vf[4];
#pragma unroll
    for (int j = 0; j < 4; ++j) vf[j] = *(const bf16x8*)(Vb0 + j * 1024 + vx);
    __builtin_amdgcn_s_setprio(1);
    lacc = __builtin_amdgcn_mfma_f32_16x16x32_bf16(pf, onesb, lacc, 0, 0, 0);
#pragma unroll
    for (int j = 0; j < 4; ++j)
      o_acc[j] = __builtin_amdgcn_mfma_f32_16x16x32_bf16(pf, vf[j], o_acc[j], 0, 0, 0);
    __builtin_amdgcn_s_setprio(0);
  }
  // lacc rows (quad*4+r) match o_acc rows exactly — per-lane rcp, no shuffles
  const int b = bh >> 4, h = bh & 15;
  f32x4 linv;
#pragma unroll
  for (int r = 0; r < 4; ++r) linv[r] = __builtin_amdgcn_rcpf(lacc[r]);
#pragma unroll
  for (int j = 0; j < 4; ++j)
#pragma unroll
    for (int r = 0; r < 4; ++r) {
      const int s = q0 + quad * 4 + r;
      const int d = h * 64 + j * 16 + rl;
      AO[((size_t)b * 2048 + s) * 1024 + d] = (bf16)(o_acc[j][r] * linv[r]);
    }
}

// ===================== output projection GEMM (transposed fp32 store) =======
__global__ __launch_bounds__(256, 2) void gemm_out_kernel(const bf16* __restrict__ AO,
                                                          const bf16* __restrict__ WoB,
                                                          const float* __restrict__ bo,
                                                          float* __restrict__ out) {
  __shared__ bf16 ldsA[128 * 64], ldsB[128 * 64];
  const int tm = blockIdx.x * 128, tn = blockIdx.y * 128;
  f32x4 acc[4][4];
  const f32x4 z = {0.f, 0.f, 0.f, 0.f};
#pragma unroll
  for (int i = 0; i < 4; ++i)
#pragma unroll
    for (int j = 0; j < 4; ++j) acc[i][j] = z;
  gemm_tile_128(AO, WoB, tm, tn, ldsA, ldsB, acc);
  const int lane = threadIdx.x & 63, wave = threadIdx.x >> 6;
  const int wm = wave >> 1, wn = wave & 1;
  const int rl = lane & 15, quad = lane >> 4;
#pragma unroll
  for (int j = 0; j < 4; ++j) {
    const int n = tn + wn * 64 + j * 16 + rl;  // = d
    const float bias = bo[n];
#pragma unroll
    for (int i = 0; i < 4; ++i) {
      const int m0 = tm + wm * 64 + i * 16 + quad * 4;
      const int b = m0 >> 11, s = m0 & 2047;
      f32x4 v = acc[i][j];
      v[0] += bias;
      v[1] += bias;
      v[2] += bias;
      v[3] += bias;
      *(f32x4*)(out + ((size_t)(b * 1024 + n)) * 2048 + s) = v;
    }
  }
}

extern "C" void kernel_launch(void* const* d_in, const int* in_sizes, int n_in,
                              void* d_out, int out_size, void* d_ws, size_t ws_size,
                              hipStream_t stream) {
  const float* x = (const float*)d_in[0];
  const float* Wq = (const float*)d_in[1];
  const float* bq = (const float*)d_in[2];
  const float* Wk = (const float*)d_in[3];
  const float* bk = (const float*)d_in[4];
  const float* Wv = (const float*)d_in[5];
  const float* bv = (const float*)d_in[6];
  const float* Wo = (const float*)d_in[7];
  const float* bo = (const float*)d_in[8];
  float* out = (float*)d_out;

  char* p = (char*)d_ws;
  bf16* xT = (bf16*)p;
  p += (size_t)NM * ND * 2;  // 16 MiB
  bf16* Wqkv = (bf16*)p;
  p += (size_t)3 * ND * ND * 2;  // 6 MiB
  bf16* WoB = (bf16*)p;
  p += (size_t)ND * ND * 2;  // 2 MiB
  bf16* Qb = (bf16*)p;
  p += (size_t)NM * ND * 2;
  bf16* Kbf = (bf16*)p;
  p += (size_t)NM * ND * 2;
  bf16* VTb = (bf16*)p;
  p += (size_t)NM * ND * 2;
  bf16* AO = xT;  // alias: xT fully consumed by gemm_qkv before attn writes AO

  prep_x_kernel<<<dim3(NS / 32, ND / 32, NB), dim3(32, 8), 0, stream>>>(x, xT);
  prep_w_kernel<<<dim3(4096), dim3(256), 0, stream>>>(Wq, Wk, Wv, Wo, Wqkv, WoB);
  gemm_qkv_kernel<<<dim3(NM / 128, 3072 / 128), dim3(256), 0, stream>>>(
      xT, Wqkv, bq, bk, bv, Qb, Kbf, VTb);
  attn_kernel<<<dim3(NB * NH, NS / 64), dim3(256), 0, stream>>>(Qb, Kbf, VTb, AO);
  gemm_out_kernel<<<dim3(NM / 128, ND / 128), dim3(256), 0, stream>>>(AO, WoB, bo, out);
}

// Round 7
// 262.029 us; speedup vs baseline: 1.1855x; 1.1855x over previous
//
#include <hip/hip_runtime.h>

// MHA forward, MI355X gfx950. B=4 D=1024 S=2048 H=16 hd=64.
// R13: attn reverted verbatim to R8 (best measured: 76.1us; R9 rotation
// neutral, R10 global-direct 243us, R11 ILP-pipeline 84us, R12 small-tile
// TLP 130us via L2 thrash -- all refuted). New this round, targeting the
// ~180us non-attn budget: (1) prep_w fused into prep_x (one launch fewer);
// (2) PE trig via __sinf/__cosf (precise libm large-angle path was
// VALU-heavy; native error ~1e-4 rad << bf16 quantum); (3) GEMM
// launch_bounds (256,2)->(256,3): m97's measured-best ran 3 blocks/CU,
// our 2 was a self-inflicted cap.

typedef __bf16 bf16;
typedef __attribute__((ext_vector_type(8))) __bf16 bf16x8;
typedef __attribute__((ext_vector_type(4))) __bf16 bf16x4;
typedef __attribute__((ext_vector_type(2))) __bf16 bf16x2;
typedef __attribute__((ext_vector_type(4))) float f32x4;
typedef __attribute__((ext_vector_type(2))) unsigned int uintx2;
typedef __attribute__((ext_vector_type(4))) unsigned int uintx4;

#define NB 4
#define ND 1024
#define NS 2048
#define NH 16
#define NM 8192  // NB*NS

__device__ __forceinline__ void gld16(const void* g, void* l) {
  __builtin_amdgcn_global_load_lds((__attribute__((address_space(1))) void*)g,
                                   (__attribute__((address_space(3))) void*)l, 16, 0, 0);
}

__device__ __forceinline__ float exp2_fast(float x) {
#if __has_builtin(__builtin_amdgcn_exp2f)
  return __builtin_amdgcn_exp2f(x);
#else
  return exp2f(x);
#endif
}

__device__ __forceinline__ unsigned pk2(float a, float b) {
  bf16x2 t;
  t[0] = (bf16)a;
  t[1] = (bf16)b;
  return __builtin_bit_cast(unsigned int, t);
}

// Exchange within lane groups {rl, rl+16, rl+32, rl+48}: perfect shuffle of
// the swapped-QK^T C-layout dwords into the PV A-operand dword layout.
__device__ __forceinline__ void lane_xchg(unsigned a, unsigned b, unsigned& lo,
                                          unsigned& hi) {
#if __has_builtin(__builtin_amdgcn_permlane32_swap) && \
    __has_builtin(__builtin_amdgcn_permlane16_swap)
  uintx2 r = __builtin_amdgcn_permlane32_swap(a, b, false, false);
  uintx2 r2 = __builtin_amdgcn_permlane16_swap(r[0], r[1], false, false);
  lo = r2[0];
  hi = r2[1];
#else
  const int lane = threadIdx.x & 63;
  const int src = (lane & 15) + ((lane >> 4) & 1) * 32;
  const unsigned as = (unsigned)__shfl((int)a, src, 64);
  const unsigned bs = (unsigned)__shfl((int)b, src, 64);
  const unsigned as2 = (unsigned)__shfl((int)a, src + 16, 64);
  const unsigned bs2 = (unsigned)__shfl((int)b, src + 16, 64);
  lo = (lane >= 32) ? bs : as;
  hi = (lane >= 32) ? bs2 : as2;
#endif
}

// ====== fused prep: z<NB -> xT[b*S+s][d] = bf16(x[b][d][s] + PE[d][s]);
//        z==NB -> Wq|Wk|Wv -> Wqkv bf16 [3072][1024], Wo -> WoB bf16
__global__ __launch_bounds__(256) void prep_kernel(
    const float* __restrict__ x, const float* __restrict__ Wq,
    const float* __restrict__ Wk, const float* __restrict__ Wv,
    const float* __restrict__ Wo, bf16* __restrict__ xT, bf16* __restrict__ Wqkv,
    bf16* __restrict__ WoB) {
  const int tx = threadIdx.x, ty = threadIdx.y;
  if (blockIdx.z == NB) {
    // weights: 2048 blocks x 256 threads x 2 chunks of 4 floats = 4M floats
    const size_t flat = ((size_t)blockIdx.y * 64 + blockIdx.x) * 256 + ty * 32 + tx;
#pragma unroll
    for (int c = 0; c < 2; ++c) {
      const size_t i = (flat * 2 + c) * 4;
      const float* src;
      bf16* dst;
      size_t off;
      if (i < (size_t)3 * 1024 * 1024) {
        const int sel = (int)(i >> 20);
        src = sel == 0 ? Wq : (sel == 1 ? Wk : Wv);
        off = i - ((size_t)sel << 20);
        dst = Wqkv + i;
      } else {
        src = Wo;
        off = i - ((size_t)3 << 20);
        dst = WoB + off;
      }
      const f32x4 v = *(const f32x4*)(src + off);
      bf16x4 o;
      o[0] = (bf16)v[0];
      o[1] = (bf16)v[1];
      o[2] = (bf16)v[2];
      o[3] = (bf16)v[3];
      *(bf16x4*)dst = o;
    }
    return;
  }
  __shared__ float t[32][33];
  const int s0 = blockIdx.x * 32, d0 = blockIdx.y * 32, b = blockIdx.z;
#pragma unroll
  for (int i = 0; i < 4; ++i) {
    const int rr = ty + i * 8;
    const int d = d0 + rr, s = s0 + tx;
    const float freq = __expf(-(float)(d >> 1) * 0.01798894603980689f);
    const float ang = (float)s * freq;
    // native trig: range-reduction err ~1e-4 rad << bf16 quantum (4e-3)
    const float pe = (d & 1) ? __cosf(ang) : __sinf(ang);
    t[rr][tx] = x[((size_t)b * ND + d) * NS + s] + pe;
  }
  __syncthreads();
#pragma unroll
  for (int i = 0; i < 4; ++i) {
    const int a = ty + i * 8;  // s offset
    xT[((size_t)b * NS + s0 + a) * ND + d0 + tx] = (bf16)t[tx][a];
  }
}

// ============ shared 128x128 GEMM mainloop, BK=64 (A [M,K], B [N,K], K=1024)
// Tiles 128 rows x 64 cols (16 KB, 128B rows), chunk^(row&7) XOR swizzle.
__device__ __forceinline__ void gemm_tile_128(const bf16* __restrict__ A,
                                              const bf16* __restrict__ Bm,
                                              int tm, int tn, bf16* ldsA, bf16* ldsB,
                                              f32x4 acc[4][4]) {
  const int tid = threadIdx.x;
  const int lane = tid & 63, wave = tid >> 6;
  const int wm = wave >> 1, wn = wave & 1;
  const int rl = lane & 15, quad = lane >> 4;
  int r0[4], c0[4];
#pragma unroll
  for (int j = 0; j < 4; ++j) {
    const int o = (wave * 4 + j) * 1024 + lane * 16;  // byte offset in 16KB tile
    const int r = o >> 7;                             // row (128B rows)
    r0[j] = r;
    c0[j] = ((((o >> 4) & 7) ^ (r & 7)) * 8);  // element col, XOR swizzled
  }
  for (int kt = 0; kt < 1024; kt += 64) {
#pragma unroll
    for (int j = 0; j < 4; ++j) {
      gld16(A + (size_t)(tm + r0[j]) * 1024 + kt + c0[j], (char*)ldsA + (wave * 4 + j) * 1024);
      gld16(Bm + (size_t)(tn + r0[j]) * 1024 + kt + c0[j], (char*)ldsB + (wave * 4 + j) * 1024);
    }
    __syncthreads();
#pragma unroll
    for (int kk = 0; kk < 2; ++kk) {
      bf16x8 af[4], bfr[4];
#pragma unroll
      for (int i = 0; i < 4; ++i) {
        const int ra = wm * 64 + i * 16 + rl;
        af[i] = *(const bf16x8*)((const char*)ldsA + ra * 128 +
                                 (((kk * 4 + quad) ^ (rl & 7)) * 16));
        const int rb = wn * 64 + i * 16 + rl;
        bfr[i] = *(const bf16x8*)((const char*)ldsB + rb * 128 +
                                  (((kk * 4 + quad) ^ (rl & 7)) * 16));
      }
#pragma unroll
      for (int i = 0; i < 4; ++i)
#pragma unroll
        for (int j = 0; j < 4; ++j)
          acc[i][j] =
              __builtin_amdgcn_mfma_f32_16x16x32_bf16(af[i], bfr[j], acc[i][j], 0, 0, 0);
    }
    __syncthreads();
  }
}

// ===================== QKV projection GEMM ==================================
__global__ __launch_bounds__(256, 3) void gemm_qkv_kernel(
    const bf16* __restrict__ xT, const bf16* __restrict__ Wqkv,
    const float* __restrict__ bq, const float* __restrict__ bk,
    const float* __restrict__ bv, bf16* __restrict__ Q, bf16* __restrict__ Kb,
    bf16* __restrict__ VT) {
  __shared__ bf16 ldsA[128 * 64], ldsB[128 * 64];
  const int tm = blockIdx.x * 128, tn = blockIdx.y * 128;
  f32x4 acc[4][4];
  const f32x4 z = {0.f, 0.f, 0.f, 0.f};
#pragma unroll
  for (int i = 0; i < 4; ++i)
#pragma unroll
    for (int j = 0; j < 4; ++j) acc[i][j] = z;
  gemm_tile_128(xT, Wqkv, tm, tn, ldsA, ldsB, acc);
  const int lane = threadIdx.x & 63, wave = threadIdx.x >> 6;
  const int wm = wave >> 1, wn = wave & 1;
  const int rl = lane & 15, quad = lane >> 4;
  // Q scale folds 1/sqrt(64) * log2(e) so attn uses raw 2^x
  const float QSCALE = 0.18033688011112042f;
#pragma unroll
  for (int j = 0; j < 4; ++j) {
    const int n = tn + wn * 64 + j * 16 + rl;  // 0..3071
    const int which = n >> 10;                 // uniform per block
    const int nl = n & 1023;
    const int h = nl >> 6, d = nl & 63;
    const float bias = (which == 0 ? bq : which == 1 ? bk : bv)[nl];
#pragma unroll
    for (int i = 0; i < 4; ++i) {
      const int m0 = tm + wm * 64 + i * 16 + quad * 4;
      const int b = m0 >> 11, s0 = m0 & 2047;
      const size_t bh = (size_t)(b * 16 + h);
      if (which == 2) {
        bf16x4 pk;
#pragma unroll
        for (int r = 0; r < 4; ++r) pk[r] = (bf16)(acc[i][j][r] + bias);
        *(bf16x4*)(VT + ((size_t)bh * 64 + d) * 2048 + s0) = pk;  // V^T packed
      } else {
#pragma unroll
        for (int r = 0; r < 4; ++r) {
          const float v = acc[i][j][r] + bias;
          const int s = s0 + r;
          if (which == 0)
            Q[(bh * 2048 + s) * 64 + d] = (bf16)(v * QSCALE);
          else
            Kb[(bh * 2048 + s) * 64 + d] = (bf16)v;
        }
      }
    }
  }
}

// ===================== flash attention (R8 verbatim, 76.1us measured) =======
// grid (B*H=64, S/128=16): bh%8 = XCD -> each head's K/V pinned to one XCD L2.
// 128 q/block, 32 q/wave, 4 blocks/CU (32 KB LDS). S^T = K*Q^T (C rows=keys,
// cols=q). P never touches LDS: exp2+bf16-pack into dwords, then
// permlane32_swap+permlane16_swap perfect-shuffles the C-layout dwords
// straight into the PV A-operand fragment. l via ones-MFMA.
__global__ __launch_bounds__(256, 4) void attn_kernel(const bf16* __restrict__ Q,
                                                      const bf16* __restrict__ Kb,
                                                      const bf16* __restrict__ VT,
                                                      bf16* __restrict__ AO) {
  __shared__ __align__(16) char smem[32768];
  char* ldsK = smem;           // 2 x 8 KB (double buffer)
  char* ldsV = smem + 16384;   // 2 x 8 KB (double buffer)
  const int tid = threadIdx.x;
  const int lane = tid & 63, wave = tid >> 6;
  const int rl = lane & 15, quad = lane >> 4;
  const int bh = blockIdx.x;
  const int q0 = blockIdx.y * 128;
  const bf16* Qb = Q + ((size_t)bh * 2048 + q0) * 64;
  const bf16* Kbb = Kb + (size_t)bh * 2048 * 64;
  const bf16* Vb = VT + (size_t)bh * 64 * 2048;
  // staging geometry: 2 x 16B chunks per thread per 8KB tile, rows 128B
  const int o0 = wave * 1024 + lane * 16, o1 = o0 + 4096;
  const int ra = o0 >> 7, rb = o1 >> 7;
  const int ca = (((o0 >> 4) & 7) ^ (ra & 7)) * 16;
  const int cb = (((o1 >> 4) & 7) ^ (rb & 7)) * 16;
  gld16((const char*)Kbb + (size_t)ra * 128 + ca, ldsK + wave * 1024);
  gld16((const char*)Kbb + (size_t)rb * 128 + cb, ldsK + wave * 1024 + 4096);
  gld16((const char*)Vb + (size_t)ra * 4096 + ca, ldsV + wave * 1024);
  gld16((const char*)Vb + (size_t)rb * 4096 + cb, ldsV + wave * 1024 + 4096);
  // Q fragments straight from global (read exactly once; aligned 16B)
  bf16x8 qf[2][2];
#pragma unroll
  for (int i = 0; i < 2; ++i)
#pragma unroll
    for (int ks = 0; ks < 2; ++ks)
      qf[i][ks] =
          *(const bf16x8*)(Qb + (wave * 32 + i * 16 + rl) * 64 + ks * 32 + quad * 8);
  f32x4 o_acc[2][4], lacc[2];  // o_acc[i=q-tile][j=d-tile]
  const f32x4 z = {0.f, 0.f, 0.f, 0.f};
#pragma unroll
  for (int i = 0; i < 2; ++i) {
    lacc[i] = z;
#pragma unroll
    for (int j = 0; j < 4; ++j) o_acc[i][j] = z;
  }
  const bf16 oneb = (bf16)1.0f;
  const bf16x8 onesb = {oneb, oneb, oneb, oneb, oneb, oneb, oneb, oneb};
  int buf = 0;
  for (int kt = 0; kt < 2048; kt += 64, buf ^= 1) {
    __syncthreads();  // K/V[buf] landed (vmcnt drain); buf^1 free for prefetch
    if (kt + 64 < 2048) {
      const int nb = (buf ^ 1) * 8192;
      gld16((const char*)Kbb + (size_t)(kt + 64 + ra) * 128 + ca, ldsK + nb + wave * 1024);
      gld16((const char*)Kbb + (size_t)(kt + 64 + rb) * 128 + cb,
            ldsK + nb + wave * 1024 + 4096);
      gld16((const char*)Vb + (size_t)ra * 4096 + (size_t)(kt + 64) * 2 + ca,
            ldsV + nb + wave * 1024);
      gld16((const char*)Vb + (size_t)rb * 4096 + (size_t)(kt + 64) * 2 + cb,
            ldsV + nb + wave * 1024 + 4096);
    }
    const char* Kbase = ldsK + buf * 8192;
    const char* Vbase = ldsV + buf * 8192;
#pragma unroll
    for (int ks = 0; ks < 2; ++ks) {
      // K fragments for the two 16-key tiles of this 32-key half
      const int jk0 = ks * 2, jk1 = ks * 2 + 1;
      const bf16x8 k00 =
          *(const bf16x8*)(Kbase + (jk0 * 16 + rl) * 128 + ((quad ^ (rl & 7)) * 16));
      const bf16x8 k01 =
          *(const bf16x8*)(Kbase + (jk0 * 16 + rl) * 128 + (((4 + quad) ^ (rl & 7)) * 16));
      const bf16x8 k10 =
          *(const bf16x8*)(Kbase + (jk1 * 16 + rl) * 128 + ((quad ^ (rl & 7)) * 16));
      const bf16x8 k11 =
          *(const bf16x8*)(Kbase + (jk1 * 16 + rl) * 128 + (((4 + quad) ^ (rl & 7)) * 16));
      bf16x8 pf[2];
#pragma unroll
      for (int i = 0; i < 2; ++i) {
        f32x4 s0 = z, s1 = z;
        s0 = __builtin_amdgcn_mfma_f32_16x16x32_bf16(k00, qf[i][0], s0, 0, 0, 0);
        s0 = __builtin_amdgcn_mfma_f32_16x16x32_bf16(k01, qf[i][1], s0, 0, 0, 0);
        s1 = __builtin_amdgcn_mfma_f32_16x16x32_bf16(k10, qf[i][0], s1, 0, 0, 0);
        s1 = __builtin_amdgcn_mfma_f32_16x16x32_bf16(k11, qf[i][1], s1, 0, 0, 0);
        // lane holds P[q=i*16+rl][key jk*16+quad*4+r] -> pack to bf16 dwords
        const unsigned a0 = pk2(exp2_fast(s0[0]), exp2_fast(s0[1]));
        const unsigned a1 = pk2(exp2_fast(s0[2]), exp2_fast(s0[3]));
        const unsigned b0 = pk2(exp2_fast(s1[0]), exp2_fast(s1[1]));
        const unsigned b1 = pk2(exp2_fast(s1[2]), exp2_fast(s1[3]));
        unsigned d0, d1, d2, d3;
        lane_xchg(a0, b0, d0, d2);  // keys 8q+{0,1} and 8q+{4,5}
        lane_xchg(a1, b1, d1, d3);  // keys 8q+{2,3} and 8q+{6,7}
        uintx4 dd;
        dd[0] = d0;
        dd[1] = d1;
        dd[2] = d2;
        dd[3] = d3;
        pf[i] = __builtin_bit_cast(bf16x8, dd);
        lacc[i] =
            __builtin_amdgcn_mfma_f32_16x16x32_bf16(pf[i], onesb, lacc[i], 0, 0, 0);
      }
#pragma unroll
      for (int j = 0; j < 4; ++j) {
        const bf16x8 vf = *(const bf16x8*)(Vbase + (j * 16 + rl) * 128 +
                                           (((ks * 4 + quad) ^ (rl & 7)) * 16));
#pragma unroll
        for (int i = 0; i < 2; ++i)
          o_acc[i][j] =
              __builtin_amdgcn_mfma_f32_16x16x32_bf16(pf[i], vf, o_acc[i][j], 0, 0, 0);
      }
    }
  }
  // lacc rows (quad*4+r) match o_acc rows exactly — per-lane rcp, no shuffles
  const int b = bh >> 4, h = bh & 15;
#pragma unroll
  for (int i = 0; i < 2; ++i) {
    f32x4 linv;
#pragma unroll
    for (int r = 0; r < 4; ++r) linv[r] = __builtin_amdgcn_rcpf(lacc[i][r]);
#pragma unroll
    for (int j = 0; j < 4; ++j)
#pragma unroll
      for (int r = 0; r < 4; ++r) {
        const int s = q0 + wave * 32 + i * 16 + quad * 4 + r;
        const int d = h * 64 + j * 16 + rl;
        AO[((size_t)b * 2048 + s) * 1024 + d] = (bf16)(o_acc[i][j][r] * linv[r]);
      }
  }
}

// ===================== output projection GEMM (transposed fp32 store) =======
__global__ __launch_bounds__(256, 3) void gemm_out_kernel(const bf16* __restrict__ AO,
                                                          const bf16* __restrict__ WoB,
                                                          const float* __restrict__ bo,
                                                          float* __restrict__ out) {
  __shared__ bf16 ldsA[128 * 64], ldsB[128 * 64];
  const int tm = blockIdx.x * 128, tn = blockIdx.y * 128;
  f32x4 acc[4][4];
  const f32x4 z = {0.f, 0.f, 0.f, 0.f};
#pragma unroll
  for (int i = 0; i < 4; ++i)
#pragma unroll
    for (int j = 0; j < 4; ++j) acc[i][j] = z;
  gemm_tile_128(AO, WoB, tm, tn, ldsA, ldsB, acc);
  const int lane = threadIdx.x & 63, wave = threadIdx.x >> 6;
  const int wm = wave >> 1, wn = wave & 1;
  const int rl = lane & 15, quad = lane >> 4;
#pragma unroll
  for (int j = 0; j < 4; ++j) {
    const int n = tn + wn * 64 + j * 16 + rl;  // = d
    const float bias = bo[n];
#pragma unroll
    for (int i = 0; i < 4; ++i) {
      const int m0 = tm + wm * 64 + i * 16 + quad * 4;
      const int b = m0 >> 11, s = m0 & 2047;
      f32x4 v = acc[i][j];
      v[0] += bias;
      v[1] += bias;
      v[2] += bias;
      v[3] += bias;
      *(f32x4*)(out + ((size_t)(b * 1024 + n)) * 2048 + s) = v;
    }
  }
}

extern "C" void kernel_launch(void* const* d_in, const int* in_sizes, int n_in,
                              void* d_out, int out_size, void* d_ws, size_t ws_size,
                              hipStream_t stream) {
  const float* x = (const float*)d_in[0];
  const float* Wq = (const float*)d_in[1];
  const float* bq = (const float*)d_in[2];
  const float* Wk = (const float*)d_in[3];
  const float* bk = (const float*)d_in[4];
  const float* Wv = (const float*)d_in[5];
  const float* bv = (const float*)d_in[6];
  const float* Wo = (const float*)d_in[7];
  const float* bo = (const float*)d_in[8];
  float* out = (float*)d_out;

  char* p = (char*)d_ws;
  bf16* xT = (bf16*)p;
  p += (size_t)NM * ND * 2;  // 16 MiB
  bf16* Wqkv = (bf16*)p;
  p += (size_t)3 * ND * ND * 2;  // 6 MiB
  bf16* WoB = (bf16*)p;
  p += (size_t)ND * ND * 2;  // 2 MiB
  bf16* Qb = (bf16*)p;
  p += (size_t)NM * ND * 2;
  bf16* Kbf = (bf16*)p;
  p += (size_t)NM * ND * 2;
  bf16* VTb = (bf16*)p;
  p += (size_t)NM * ND * 2;
  bf16* AO = xT;  // alias: xT fully consumed by gemm_qkv before attn writes AO

  prep_kernel<<<dim3(NS / 32, ND / 32, NB + 1), dim3(32, 8), 0, stream>>>(
      x, Wq, Wk, Wv, Wo, xT, Wqkv, WoB);
  gemm_qkv_kernel<<<dim3(NM / 128, 3072 / 128), dim3(256), 0, stream>>>(
      xT, Wqkv, bq, bk, bv, Qb, Kbf, VTb);
  attn_kernel<<<dim3(NB * NH, NS / 128), dim3(256), 0, stream>>>(Qb, Kbf, VTb, AO);
  gemm_out_kernel<<<dim3(NM / 128, ND / 128), dim3(256), 0, stream>>>(AO, WoB, bo, out);
}